// Round 3
// baseline (417.132 us; speedup 1.0000x reference)
//
#include <hip/hip_runtime.h>

#define IMG_H 256
#define IMG_W 256
#define IMG_C 3
#define KS 33
#define PAD 16
#define THRESH 1e-4f
#define FH_PER 3                   // 33 fh values in 11 chunks of 3
#define RPB 2                      // image rows per block
#define PADW (IMG_W + 2 * PAD)     // 288 padded row width
#define WROWS (RPB + FH_PER - 1)   // 4 window rows per channel (pow2!)
#define NROWS (IMG_C * WROWS)      // 12 staged rows

// Block: 128 threads (2 waves). Thread t: row r=t>>6, 4 px at x4=(t&63)*4.
// Grid: (128 row-pairs, 11 fh-chunks) = 1408 blocks = 5.5 blocks/CU, 11 waves/CU.
// Kernels streamed as aligned float4 (1 KB/wave-instr). Image rows staged in LDS
// with replication padding baked in. dfh loop kept rolled (#pragma unroll 1) and
// __launch_bounds__(128,3) -> ~170 VGPR budget: avoid R2's spill regression.
__global__ __launch_bounds__(128, 3)
void reblur_kernel(const float* __restrict__ img,
                   const float* __restrict__ ker,
                   float* __restrict__ out)
{
    __shared__ float lds[NROWS * PADW];   // 12*288*4 = 13824 B

    const int tid = threadIdx.x;          // 0..127
    const int y0 = blockIdx.x * RPB;
    const int fh0 = blockIdx.y * FH_PER;
    const int plane = IMG_H * IMG_W;

    // ---- Stage 12 replication-padded rows (4 window rows x 3 channels) ----
    const int ybase = y0 + fh0 - PAD;
    #pragma unroll
    for (int row = 0; row < NROWS; ++row) {
        const int ch = row >> 2;                 // /WROWS (=4)
        const int rw = row & (WROWS - 1);
        int yy = ybase + rw;
        yy = yy < 0 ? 0 : (yy > IMG_H - 1 ? IMG_H - 1 : yy);
        const float* __restrict__ src = img + ch * plane + yy * IMG_W;
        float* dst = lds + row * PADW;
        for (int p = tid; p < PADW; p += 128) {
            int sc = p - PAD;
            sc = sc < 0 ? 0 : (sc > IMG_W - 1 ? IMG_W - 1 : sc);
            dst[p] = src[sc];
        }
    }
    __syncthreads();

    // ---- Compute: 4 px/thread, float4 kernel-weight stream ----
    const int r = tid >> 6;          // row within block
    const int l = tid & 63;          // lane
    const int x4 = l << 2;
    const int y = y0 + r;

    const float4* __restrict__ ker4 = (const float4*)ker;
    const int qplane = plane / 4;    // 16384 float4s per tap plane
    const size_t kbase = (size_t)(fh0 * KS) * qplane + (size_t)y * (IMG_W / 4) + l;

    float acc[IMG_C][4];
    #pragma unroll
    for (int c = 0; c < IMG_C; ++c)
        #pragma unroll
        for (int p = 0; p < 4; ++p) acc[c][p] = 0.f;

    #pragma unroll 1                 // keep body at 33 taps: register pressure
    for (int dfh = 0; dfh < FH_PER; ++dfh) {
        int woff[IMG_C];
        float win[IMG_C][8];
        #pragma unroll
        for (int c = 0; c < IMG_C; ++c) {
            woff[c] = (c * WROWS + r + dfh) * PADW + x4;
            float4 t0 = *(const float4*)&lds[woff[c]];
            win[c][0] = t0.x; win[c][1] = t0.y; win[c][2] = t0.z; win[c][3] = t0.w;
        }
        const size_t kb = kbase + (size_t)(dfh * KS) * qplane;

        #pragma unroll
        for (int g = 0; g < 8; ++g) {        // fw = 4g+j
            float4 kw[4];
            #pragma unroll
            for (int j = 0; j < 4; ++j)
                kw[j] = ker4[kb + (size_t)(4 * g + j) * qplane];
            #pragma unroll
            for (int c = 0; c < IMG_C; ++c) {
                float4 t1 = *(const float4*)&lds[woff[c] + 4 * (g + 1)];
                win[c][4] = t1.x; win[c][5] = t1.y; win[c][6] = t1.z; win[c][7] = t1.w;
            }
            #pragma unroll
            for (int j = 0; j < 4; ++j) {
                float w0 = kw[j].x > THRESH ? kw[j].x : 0.f;
                float w1 = kw[j].y > THRESH ? kw[j].y : 0.f;
                float w2 = kw[j].z > THRESH ? kw[j].z : 0.f;
                float w3 = kw[j].w > THRESH ? kw[j].w : 0.f;
                #pragma unroll
                for (int c = 0; c < IMG_C; ++c) {
                    acc[c][0] = fmaf(w0, win[c][j + 0], acc[c][0]);
                    acc[c][1] = fmaf(w1, win[c][j + 1], acc[c][1]);
                    acc[c][2] = fmaf(w2, win[c][j + 2], acc[c][2]);
                    acc[c][3] = fmaf(w3, win[c][j + 3], acc[c][3]);
                }
            }
            #pragma unroll
            for (int c = 0; c < IMG_C; ++c) {   // rotate window
                win[c][0] = win[c][4]; win[c][1] = win[c][5];
                win[c][2] = win[c][6]; win[c][3] = win[c][7];
            }
        }
        {   // fw = 32: window [32..35] is current win[c][0..3]
            float4 kw = ker4[kb + (size_t)32 * qplane];
            float w0 = kw.x > THRESH ? kw.x : 0.f;
            float w1 = kw.y > THRESH ? kw.y : 0.f;
            float w2 = kw.z > THRESH ? kw.z : 0.f;
            float w3 = kw.w > THRESH ? kw.w : 0.f;
            #pragma unroll
            for (int c = 0; c < IMG_C; ++c) {
                acc[c][0] = fmaf(w0, win[c][0], acc[c][0]);
                acc[c][1] = fmaf(w1, win[c][1], acc[c][1]);
                acc[c][2] = fmaf(w2, win[c][2], acc[c][2]);
                acc[c][3] = fmaf(w3, win[c][3], acc[c][3]);
            }
        }
    }

    // ---- Accumulate (out zeroed by memset; 11 chunks collide per address) ----
    float* op = out + y * IMG_W + x4;
    #pragma unroll
    for (int c = 0; c < IMG_C; ++c)
        #pragma unroll
        for (int p = 0; p < 4; ++p)
            atomicAdd(op + c * plane + p, acc[c][p]);
}

extern "C" void kernel_launch(void* const* d_in, const int* in_sizes, int n_in,
                              void* d_out, int out_size, void* d_ws, size_t ws_size,
                              hipStream_t stream) {
    const float* img = (const float*)d_in[0];   // [1,3,256,256] fp32
    const float* ker = (const float*)d_in[1];   // [1,1089,256,256] fp32
    float* out = (float*)d_out;                 // [1,3,256,256] fp32

    hipMemsetAsync(out, 0, (size_t)out_size * sizeof(float), stream);

    dim3 grid(IMG_H / RPB, KS / FH_PER);        // (128, 11)
    reblur_kernel<<<grid, 128, 0, stream>>>(img, ker, out);
}

// Round 4
// 387.395 us; speedup vs baseline: 1.0768x; 1.0768x over previous
//
#include <hip/hip_runtime.h>

#define IMG_W 256
#define IMG_H 256
#define KS 33
#define PAD 16
#define THRESH 1e-4f
#define FH_PER 3
#define NCHUNK 11                  // 33/3
#define RPB 2                      // image rows per block
#define PADW (IMG_W + 2 * PAD)     // 288
#define WROWS (RPB + FH_PER - 1)   // 4 window rows per channel
#define PLANE (IMG_H * IMG_W)      // 65536
#define QROW (IMG_W / 2)           // 128 float2 per row

// Main kernel: grid (128 row-pairs, 11 fh-chunks), 256 threads.
// Thread t: row r=t>>7, i=t&127, pixels {2i, 2i+1}. Wave = 512 B contiguous ker
// float2 stream (only HBM traffic in the vmcnt queue). Image rows staged padded
// in LDS (lgkmcnt — decoupled from ker stream). Partials to ws, no atomics.
__global__ __launch_bounds__(256, 6)
void reblur_partial(const float* __restrict__ img,
                    const float* __restrict__ ker,
                    float* __restrict__ ws)
{
    __shared__ float lds[3 * WROWS * PADW];   // 3456 floats = 13.8 KB

    const int tid = threadIdx.x;
    const int y0 = blockIdx.x * RPB;
    const int fh0 = blockIdx.y * FH_PER;

    // ---- stage 12 replication-padded rows ----
    const int ybase = y0 + fh0 - PAD;
    #pragma unroll
    for (int row = 0; row < 3 * WROWS; ++row) {
        const int ch = row >> 2;              // / WROWS
        const int rw = row & (WROWS - 1);
        int yy = ybase + rw;
        yy = yy < 0 ? 0 : (yy > IMG_H - 1 ? IMG_H - 1 : yy);
        const float* __restrict__ src = img + ch * PLANE + yy * IMG_W;
        float* dst = lds + row * PADW;
        for (int p = tid; p < PADW; p += 256) {
            int sc = p - PAD;
            sc = sc < 0 ? 0 : (sc > IMG_W - 1 ? IMG_W - 1 : sc);
            dst[p] = src[sc];
        }
    }
    __syncthreads();

    const int r = tid >> 7;           // 0..1
    const int i = tid & 127;          // 0..127
    const int y = y0 + r;
    const int x2 = 2 * i;

    const float2* __restrict__ ker2 = (const float2*)ker;
    const size_t kbase = (size_t)(fh0 * KS) * (PLANE / 2) + (size_t)y * QROW + i;

    float a0[3] = {0.f, 0.f, 0.f};    // pixel 2i   accum per channel
    float a1[3] = {0.f, 0.f, 0.f};    // pixel 2i+1 accum per channel

    #pragma unroll 1
    for (int dfh = 0; dfh < FH_PER; ++dfh) {
        const float* __restrict__ b0 = lds + (0 * WROWS + r + dfh) * PADW + x2;
        const float* __restrict__ b1 = lds + (1 * WROWS + r + dfh) * PADW + x2;
        const float* __restrict__ b2 = lds + (2 * WROWS + r + dfh) * PADW + x2;
        const size_t kb = kbase + (size_t)(dfh * KS) * (PLANE / 2);

        // window v[c][0..3] = padded[x2+2g .. x2+2g+3]  (8B-aligned b64 reads)
        float v[3][4];
        {
            float2 t;
            t = *(const float2*)(b0 + 0); v[0][0] = t.x; v[0][1] = t.y;
            t = *(const float2*)(b0 + 2); v[0][2] = t.x; v[0][3] = t.y;
            t = *(const float2*)(b1 + 0); v[1][0] = t.x; v[1][1] = t.y;
            t = *(const float2*)(b1 + 2); v[1][2] = t.x; v[1][3] = t.y;
            t = *(const float2*)(b2 + 0); v[2][0] = t.x; v[2][1] = t.y;
            t = *(const float2*)(b2 + 2); v[2][2] = t.x; v[2][3] = t.y;
        }

        #pragma unroll
        for (int g = 0; g < 16; ++g) {     // taps fw = 2g, 2g+1
            float2 kwa = ker2[kb + (size_t)(2 * g)     * (PLANE / 2)];
            float2 kwb = ker2[kb + (size_t)(2 * g + 1) * (PLANE / 2)];
            float wa0 = kwa.x > THRESH ? kwa.x : 0.f;   // tap 2g,   px0
            float wa1 = kwa.y > THRESH ? kwa.y : 0.f;   // tap 2g,   px1
            float wb0 = kwb.x > THRESH ? kwb.x : 0.f;   // tap 2g+1, px0
            float wb1 = kwb.y > THRESH ? kwb.y : 0.f;   // tap 2g+1, px1
            #pragma unroll
            for (int c = 0; c < 3; ++c) {
                a0[c] = fmaf(wa0, v[c][0], a0[c]);
                a1[c] = fmaf(wa1, v[c][1], a1[c]);
                a0[c] = fmaf(wb0, v[c][1], a0[c]);
                a1[c] = fmaf(wb1, v[c][2], a1[c]);
            }
            // slide window by 2 (skip LDS read past the row on the last step)
            #pragma unroll
            for (int c = 0; c < 3; ++c) { v[c][0] = v[c][2]; v[c][1] = v[c][3]; }
            if (g < 15) {
                float2 t;
                t = *(const float2*)(b0 + 2 * g + 4); v[0][2] = t.x; v[0][3] = t.y;
                t = *(const float2*)(b1 + 2 * g + 4); v[1][2] = t.x; v[1][3] = t.y;
                t = *(const float2*)(b2 + 2 * g + 4); v[2][2] = t.x; v[2][3] = t.y;
            }
        }
        {   // tap fw = 32: window now holds padded[x2+32 .. x2+33] in v[c][0..1]
            float2 kw = ker2[kb + (size_t)32 * (PLANE / 2)];
            float w0 = kw.x > THRESH ? kw.x : 0.f;
            float w1 = kw.y > THRESH ? kw.y : 0.f;
            #pragma unroll
            for (int c = 0; c < 3; ++c) {
                a0[c] = fmaf(w0, v[c][0], a0[c]);
                a1[c] = fmaf(w1, v[c][1], a1[c]);
            }
        }
    }

    // ---- store partials: ws[(chunk*3 + c)*PLANE + y*256 + x2] ----
    float* wp = ws + (size_t)(blockIdx.y * 3) * PLANE + (size_t)y * IMG_W + x2;
    #pragma unroll
    for (int c = 0; c < 3; ++c) {
        float2 o; o.x = a0[c]; o.y = a1[c];
        *(float2*)(wp + (size_t)c * PLANE) = o;
    }
}

// Reduce 11 chunk-partials -> out. 49152 float4s.
__global__ __launch_bounds__(256)
void reduce_partials(const float* __restrict__ ws, float* __restrict__ out)
{
    const int gid = blockIdx.x * 256 + threadIdx.x;     // 0 .. 49151
    const float4* __restrict__ w4 = (const float4*)ws;
    float4 s = w4[gid];
    #pragma unroll
    for (int c = 1; c < NCHUNK; ++c) {
        float4 t = w4[(size_t)c * (3 * PLANE / 4) + gid];
        s.x += t.x; s.y += t.y; s.z += t.z; s.w += t.w;
    }
    ((float4*)out)[gid] = s;
}

extern "C" void kernel_launch(void* const* d_in, const int* in_sizes, int n_in,
                              void* d_out, int out_size, void* d_ws, size_t ws_size,
                              hipStream_t stream) {
    const float* img = (const float*)d_in[0];   // [1,3,256,256] fp32
    const float* ker = (const float*)d_in[1];   // [1,1089,256,256] fp32
    float* out = (float*)d_out;                 // [1,3,256,256] fp32
    float* ws  = (float*)d_ws;                  // 11*3*65536 fp32 partials (8.6 MB)

    dim3 grid(IMG_H / RPB, NCHUNK);             // (128, 11)
    reblur_partial<<<grid, 256, 0, stream>>>(img, ker, ws);
    reduce_partials<<<3 * PLANE / 4 / 256, 256, 0, stream>>>(ws, out);
}